// Round 11
// baseline (1934.009 us; speedup 1.0000x reference)
//
#include <hip/hip_runtime.h>
#include <hip/hip_bf16.h>

typedef __bf16 bf16x8 __attribute__((ext_vector_type(8)));
typedef float f32x4 __attribute__((ext_vector_type(4)));

#define BATCH 65536
#define NL 256    // N_LSTM
#define NZ 1024   // 4*N_LSTM
#define FEAT 5
#define ROWS 64   // batch rows per block
#define COLS 128  // gate-cols per block (CGRP=2)
#define KTOT 288  // 256 (h@U) + 32 (x@W folded: 5 real + 27 zero)
#define ASTRIDE 296  // A_sh row stride (bf16); 592B -> rotated banks
#define TSTR 132     // t_sh row stride (f32); 528B, 16B-aligned rows
#define CGRP 2

__device__ __forceinline__ unsigned short f2bf(float f) {
  __hip_bfloat16 h = __float2bfloat16(f);  // RTNE
  return __builtin_bit_cast(unsigned short, h);
}
__device__ __forceinline__ float sigm(float z) {
  return __builtin_amdgcn_rcpf(1.f + __builtin_amdgcn_exp2f(z * -1.4426950408889634f));
}

__global__ __launch_bounds__(256) void k_prep(const float* __restrict__ U,
                                              unsigned short* __restrict__ Ut) {
  __shared__ float t[32][33];
  const int bk = blockIdx.x >> 5;
  const int bn = blockIdx.x & 31;
  const int r = threadIdx.x >> 5;
  const int c = threadIdx.x & 31;
#pragma unroll
  for (int i = 0; i < 4; ++i)
    t[r + 8 * i][c] = U[(size_t)(bk * 32 + r + 8 * i) * NZ + bn * 32 + c];
  __syncthreads();
#pragma unroll
  for (int i = 0; i < 4; ++i)
    Ut[(size_t)(bn * 32 + r + 8 * i) * KTOT + bk * 32 + c] = f2bf(t[c][r + 8 * i]);
}

__global__ __launch_bounds__(1024) void k_prepx(const float* __restrict__ W,
                                                const float* __restrict__ Wd,
                                                unsigned short* __restrict__ Ut,
                                                unsigned short* __restrict__ WdTg) {
  const int idx = blockIdx.x * 1024 + threadIdx.x;
  const int n = idx >> 5;
  const int cc = idx & 31;
  Ut[(size_t)n * KTOT + 256 + cc] = (cc < FEAT) ? f2bf(W[(size_t)cc * NZ + n]) : (unsigned short)0;
  if (blockIdx.x < 4) {
    const int p = idx >> 8;
    const int j = idx & 255;
    WdTg[p * 256 + j] = (p < FEAT) ? f2bf(Wd[(size_t)j * FEAT + p]) : (unsigned short)0;
  }
}

// ---------- shared building blocks (copy-fidelity with real kernel) ----------
#define STAGE_TILE(m0_)                                                           \
  {                                                                               \
    float4 sv[8];                                                                 \
    _Pragma("unroll") for (int it = 0; it < 8; ++it) {                            \
      const int fi = it * 512 + tid;                                              \
      const int row = fi >> 6, c4 = fi & 63;                                      \
      sv[it] = *reinterpret_cast<const float4*>(h0 + (size_t)((m0_) + row) * NL + c4 * 4); \
    }                                                                             \
    float xv[4];                                                                  \
    _Pragma("unroll") for (int it = 0; it < 4; ++it) {                            \
      const int idx = it * 512 + tid;                                             \
      const int row = idx >> 5, cc = idx & 31;                                    \
      xv[it] = (cc < FEAT) ? x[(size_t)((m0_) + row) * FEAT + cc] : 0.f;          \
    }                                                                             \
    _Pragma("unroll") for (int it = 0; it < 8; ++it) {                            \
      const int fi = it * 512 + tid;                                              \
      const int row = fi >> 6, c4 = fi & 63;                                      \
      *reinterpret_cast<ushort4*>(&A_sh[row * ASTRIDE + c4 * 4]) =                \
          make_ushort4(f2bf(sv[it].x), f2bf(sv[it].y), f2bf(sv[it].z), f2bf(sv[it].w)); \
    }                                                                             \
    _Pragma("unroll") for (int it = 0; it < 4; ++it) {                            \
      const int idx = it * 512 + tid;                                             \
      const int row = idx >> 5, cc = idx & 31;                                    \
      A_sh[row * ASTRIDE + 256 + cc] = f2bf(xv[it]);                              \
    }                                                                             \
  }

#define KLOOP_BODY()                                                              \
  _Pragma("unroll") for (int kk = 0; kk < 9; ++kk) {                              \
    bf16x8 bf[4];                                                                 \
    _Pragma("unroll") for (int g = 0; g < 4; ++g)                                 \
        bf[g] = *reinterpret_cast<const bf16x8*>(bp[g] + kk * 32);                \
    __builtin_amdgcn_sched_group_barrier(0x20, 4, 0);                             \
    bf16x8 af[4];                                                                 \
    _Pragma("unroll") for (int r = 0; r < 4; ++r)                                 \
        af[r] = *reinterpret_cast<const bf16x8*>(                                 \
            &A_sh[(r * 16 + lrow) * ASTRIDE + kk * 32 + lk8]);                    \
    __builtin_amdgcn_sched_group_barrier(0x100, 4, 0);                            \
    _Pragma("unroll") for (int g = 0; g < 4; ++g)                                 \
        _Pragma("unroll") for (int r = 0; r < 4; ++r)                             \
            acc[r][g] = __builtin_amdgcn_mfma_f32_16x16x32_bf16(af[r], bf[g], acc[r][g], 0, 0, 0); \
    __builtin_amdgcn_sched_group_barrier(0x8, 16, 0);                             \
  }

// ---------------- ablation: staging only, 12 distinct tiles ----------------
__global__ __launch_bounds__(512, 4) void k_stage(
    const float* __restrict__ x, const float* __restrict__ h0,
    float* __restrict__ junk) {
  __shared__ __align__(16) unsigned short A_sh[ROWS * ASTRIDE];
  const int tid = threadIdx.x;
  float sink = 0.f;
#pragma unroll 1
  for (int rep = 0; rep < 12; ++rep) {
    const int tile = ((int)(blockIdx.x >> 1) + rep * 409) & 1023;
    const int m0 = tile * ROWS;
    STAGE_TILE(m0)
    __syncthreads();
    sink += (float)A_sh[(tid * 37) & 16383];
    __syncthreads();
  }
  if (tid == 0) junk[blockIdx.x] = sink;
}

// ---------------- ablation: staging + k-loop, 6 distinct tiles ----------------
__global__ __launch_bounds__(512, 4) void k_sk(
    const float* __restrict__ x, const float* __restrict__ h0,
    const unsigned short* __restrict__ Ut, float* __restrict__ junk) {
  __shared__ __align__(16) unsigned short A_sh[ROWS * ASTRIDE];
  const int tid = threadIdx.x;
  const int w = tid >> 6;
  const int l = tid & 63;
  const int lrow = l & 15;
  const int lk8 = (l >> 4) * 8;
  const int cg = blockIdx.x & 1;
  const int jcol = cg * COLS + w * 16 + lrow;
  const unsigned short* bp[4];
#pragma unroll
  for (int g = 0; g < 4; ++g) bp[g] = Ut + (size_t)(g * 256 + jcol) * KTOT + lk8;
  float sink = 0.f;
#pragma unroll 1
  for (int rep = 0; rep < 6; ++rep) {
    const int tile = ((int)(blockIdx.x >> 1) + rep * 409) & 1023;
    const int m0 = tile * ROWS;
    STAGE_TILE(m0)
    __syncthreads();
    f32x4 acc[4][4];
#pragma unroll
    for (int r = 0; r < 4; ++r)
#pragma unroll
      for (int g = 0; g < 4; ++g) acc[r][g] = (f32x4){0.f, 0.f, 0.f, 0.f};
    KLOOP_BODY()
#pragma unroll
    for (int r = 0; r < 4; ++r)
#pragma unroll
      for (int g = 0; g < 4; ++g)
        sink += acc[r][g][0] + acc[r][g][1] + acc[r][g][2] + acc[r][g][3];
    __syncthreads();
  }
  if (tid == 0) junk[blockIdx.x] = sink;
}

// ---------- ablation: staging + k-loop + c0 + gates (no stores), 5 tiles ----------
__global__ __launch_bounds__(512, 4) void k_ske(
    const float* __restrict__ x, const float* __restrict__ h0,
    const float* __restrict__ c0, const float* __restrict__ b,
    const unsigned short* __restrict__ Ut, float* __restrict__ junk) {
  __shared__ __align__(16) unsigned short A_sh[ROWS * ASTRIDE];
  const int tid = threadIdx.x;
  const int w = tid >> 6;
  const int l = tid & 63;
  const int lrow = l & 15;
  const int lk8 = (l >> 4) * 8;
  const int lq = (l >> 4) * 4;
  const int cg = blockIdx.x & 1;
  const int jcol = cg * COLS + w * 16 + lrow;
  const unsigned short* bp[4];
#pragma unroll
  for (int g = 0; g < 4; ++g) bp[g] = Ut + (size_t)(g * 256 + jcol) * KTOT + lk8;
  float bb[4];
#pragma unroll
  for (int g = 0; g < 4; ++g) bb[g] = b[g * 256 + jcol];
  float sink = 0.f;
#pragma unroll 1
  for (int rep = 0; rep < 5; ++rep) {
    const int tile = ((int)(blockIdx.x >> 1) + rep * 409) & 1023;
    const int m0 = tile * ROWS;
    STAGE_TILE(m0)
    __syncthreads();
    f32x4 acc[4][4];
#pragma unroll
    for (int r = 0; r < 4; ++r)
#pragma unroll
      for (int g = 0; g < 4; ++g) acc[r][g] = (f32x4){0.f, 0.f, 0.f, 0.f};
    KLOOP_BODY()
    float c0v[4][4];
#pragma unroll
    for (int r = 0; r < 4; ++r)
#pragma unroll
      for (int v = 0; v < 4; ++v)
        c0v[r][v] = c0[(size_t)(m0 + r * 16 + lq + v) * NL + jcol];
#pragma unroll
    for (int r = 0; r < 4; ++r) {
#pragma unroll
      for (int v = 0; v < 4; ++v) {
        const float zi = acc[r][0][v] + bb[0];
        const float zf = acc[r][1][v] + bb[1];
        const float zc = acc[r][2][v] + bb[2];
        const float zo = acc[r][3][v] + bb[3];
        const float ig = sigm(zi);
        const float fg = sigm(zf);
        const float og = sigm(zo);
        const float rc = fmaxf(zc, 0.f);
        const float cv = fg * c0v[r][v] + ig * rc;
        const float hv = og * fmaxf(cv, 0.f);
        sink += cv + hv;
      }
    }
    __syncthreads();
  }
  if (tid == 0) junk[blockIdx.x] = sink;
}

// ---------------- real kernel: R10 + c routed through LDS ----------------
__global__ __launch_bounds__(512, 4) void k_lstm(
    const float* __restrict__ x, const float* __restrict__ h0,
    const float* __restrict__ c0, const float* __restrict__ b,
    const float* __restrict__ bd, const unsigned short* __restrict__ Ut,
    const unsigned short* __restrict__ WdTg, float* __restrict__ out) {
  float* out_logits = out;
  float* out_h = out + (size_t)BATCH * FEAT;
  float* out_c = out_h + (size_t)BATCH * NL;

  __shared__ __align__(16) unsigned short A_sh[ROWS * ASTRIDE];  // 37.9 KB (reused)

  const int tid = threadIdx.x;
  const int w = tid >> 6;
  const int l = tid & 63;
  const int lrow = l & 15;
  const int lk8 = (l >> 4) * 8;
  const int lq = (l >> 4) * 4;
  const int cg = blockIdx.x & 1;
  const int m0 = (blockIdx.x >> 1) * ROWS;
  const int jcol = cg * COLS + w * 16 + lrow;
  const int wcol = w * 16 + lrow;

  STAGE_TILE(m0)
  __syncthreads();

  float bb[4];
#pragma unroll
  for (int g = 0; g < 4; ++g) bb[g] = b[g * 256 + jcol];

  f32x4 acc[4][4];
#pragma unroll
  for (int r = 0; r < 4; ++r)
#pragma unroll
    for (int g = 0; g < 4; ++g) acc[r][g] = (f32x4){0.f, 0.f, 0.f, 0.f};

  const unsigned short* bp[4];
#pragma unroll
  for (int g = 0; g < 4; ++g) bp[g] = Ut + (size_t)(g * 256 + jcol) * KTOT + lk8;

  KLOOP_BODY()

  float c0v[4][4];
#pragma unroll
  for (int r = 0; r < 4; ++r)
#pragma unroll
    for (int v = 0; v < 4; ++v)
      c0v[r][v] = c0[(size_t)(m0 + r * 16 + lq + v) * NL + jcol];

  __syncthreads();  // k-loop A_sh reads done -> reuse as f32 t_sh
  float* t_sh = reinterpret_cast<float*>(A_sh);  // [64][132] f32 = 33.8 KB

  // gates: h -> t_sh (scattered LDS), c kept in regs
  float cvs[4][4];
#pragma unroll
  for (int r = 0; r < 4; ++r) {
#pragma unroll
    for (int v = 0; v < 4; ++v) {
      const int mloc = r * 16 + lq + v;
      const float zi = acc[r][0][v] + bb[0];
      const float zf = acc[r][1][v] + bb[1];
      const float zc = acc[r][2][v] + bb[2];
      const float zo = acc[r][3][v] + bb[3];
      const float ig = sigm(zi);
      const float fg = sigm(zf);
      const float og = sigm(zo);
      const float rc = fmaxf(zc, 0.f);
      const float cv = fg * c0v[r][v] + ig * rc;
      const float hv = og * fmaxf(cv, 0.f);
      cvs[r][v] = cv;
      t_sh[mloc * TSTR + wcol] = hv;
    }
  }
  __syncthreads();

  // coalesced h stores + logits (both read t_sh = h)
#pragma unroll
  for (int it = 0; it < 4; ++it) {
    const int fi = it * 512 + tid;  // 2048 float4 = 64 rows x 32
    const int row = fi >> 5, c4 = fi & 31;
    const float4 hv4 = *reinterpret_cast<const float4*>(&t_sh[row * TSTR + c4 * 4]);
    *reinterpret_cast<float4*>(out_h + (size_t)(m0 + row) * NL + cg * COLS + c4 * 4) = hv4;
  }
  if (w < 4) {
    f32x4 lacc = (f32x4){0.f, 0.f, 0.f, 0.f};
#pragma unroll
    for (int kk2 = 0; kk2 < 4; ++kk2) {
      const float4 hlo = *reinterpret_cast<const float4*>(
          &t_sh[(w * 16 + lrow) * TSTR + kk2 * 32 + lk8]);
      const float4 hhi = *reinterpret_cast<const float4*>(
          &t_sh[(w * 16 + lrow) * TSTR + kk2 * 32 + lk8 + 4]);
      bf16x8 ah;
      ah[0] = (__bf16)hlo.x; ah[1] = (__bf16)hlo.y;
      ah[2] = (__bf16)hlo.z; ah[3] = (__bf16)hlo.w;
      ah[4] = (__bf16)hhi.x; ah[5] = (__bf16)hhi.y;
      ah[6] = (__bf16)hhi.z; ah[7] = (__bf16)hhi.w;
      const bf16x8 bw = *reinterpret_cast<const bf16x8*>(
          &WdTg[lrow * 256 + cg * COLS + kk2 * 32 + lk8]);
      lacc = __builtin_amdgcn_mfma_f32_16x16x32_bf16(ah, bw, lacc, 0, 0, 0);
    }
    if (lrow < FEAT) {
      const float addv = (cg == 0) ? bd[lrow] : 0.f;
#pragma unroll
      for (int v = 0; v < 4; ++v)
        atomicAdd(&out_logits[(size_t)(m0 + w * 16 + lq + v) * FEAT + lrow],
                  lacc[v] + addv);
    }
  }
  __syncthreads();  // h reads done -> overwrite t_sh with c

#pragma unroll
  for (int r = 0; r < 4; ++r)
#pragma unroll
    for (int v = 0; v < 4; ++v)
      t_sh[(r * 16 + lq + v) * TSTR + wcol] = cvs[r][v];
  __syncthreads();

#pragma unroll
  for (int it = 0; it < 4; ++it) {
    const int fi = it * 512 + tid;
    const int row = fi >> 5, c4 = fi & 31;
    const float4 cv4 = *reinterpret_cast<const float4*>(&t_sh[row * TSTR + c4 * 4]);
    *reinterpret_cast<float4*>(out_c + (size_t)(m0 + row) * NL + cg * COLS + c4 * 4) = cv4;
  }
}

extern "C" void kernel_launch(void* const* d_in, const int* in_sizes, int n_in,
                              void* d_out, int out_size, void* d_ws, size_t ws_size,
                              hipStream_t stream) {
  const float* x = (const float*)d_in[0];
  const float* h0 = (const float*)d_in[1];
  const float* c0 = (const float*)d_in[2];
  const float* W = (const float*)d_in[3];
  const float* U = (const float*)d_in[4];
  const float* b = (const float*)d_in[5];
  const float* Wd = (const float*)d_in[6];
  const float* bd = (const float*)d_in[7];
  unsigned short* Ut = (unsigned short*)d_ws;     // 576 KB
  unsigned short* WdTg = Ut + (size_t)NZ * KTOT;  // +8 KB
  float* junk = (float*)(WdTg + 16 * 256);        // +8 KB scratch for ablation sinks

  k_prep<<<256, 256, 0, stream>>>(U, Ut);
  k_prepx<<<32, 1024, 0, stream>>>(W, Wd, Ut, WdTg);

  const int grid = (BATCH / ROWS) * CGRP;  // 2048
  // ---- measurement dispatches (write only junk scratch; read per-dispatch rows)
  k_stage<<<grid, 512, 0, stream>>>(x, h0, junk);
  k_sk<<<grid, 512, 0, stream>>>(x, h0, Ut, junk);
  k_ske<<<grid, 512, 0, stream>>>(x, h0, c0, b, Ut, junk);
  // ---- real output
  hipMemsetAsync(d_out, 0, (size_t)BATCH * FEAT * sizeof(float), stream);
  k_lstm<<<grid, 512, 0, stream>>>(x, h0, c0, b, bd, Ut, WdTg, (float*)d_out);
}

// Round 12
// 131.765 us; speedup vs baseline: 14.6777x; 14.6777x over previous
//
#include <hip/hip_runtime.h>
#include <hip/hip_bf16.h>

typedef __bf16 bf16x8 __attribute__((ext_vector_type(8)));
typedef float f32x4 __attribute__((ext_vector_type(4)));

#define BATCH 65536
#define NL 256    // N_LSTM
#define NZ 1024   // 4*N_LSTM
#define FEAT 5
#define ROWS 64   // batch rows per block
#define COLS 64   // gate-cols per block
#define CGRP 4    // col-groups per row tile
#define KTOT 288  // 256 (h@U) + 32 (x@W folded: 5 real + 27 zero)
#define ASTRIDE 296  // A_sh row stride (bf16); 592B -> rotated banks
#define TSTR 68      // t_sh row stride (f32); 272B, 16B-aligned, rotated banks

__device__ __forceinline__ unsigned short f2bf(float f) {
  __hip_bfloat16 h = __float2bfloat16(f);  // RTNE
  return __builtin_bit_cast(unsigned short, h);
}
__device__ __forceinline__ float sigm(float z) {
  return __builtin_amdgcn_rcpf(1.f + __builtin_amdgcn_exp2f(z * -1.4426950408889634f));
}

// U [256][1024] f32 -> Ut [1024][288] bf16 rows k=0..255 (transposed, k-contiguous)
__global__ __launch_bounds__(256) void k_prep(const float* __restrict__ U,
                                              unsigned short* __restrict__ Ut) {
  __shared__ float t[32][33];
  const int bk = blockIdx.x >> 5;
  const int bn = blockIdx.x & 31;
  const int r = threadIdx.x >> 5;
  const int c = threadIdx.x & 31;
#pragma unroll
  for (int i = 0; i < 4; ++i)
    t[r + 8 * i][c] = U[(size_t)(bk * 32 + r + 8 * i) * NZ + bn * 32 + c];
  __syncthreads();
#pragma unroll
  for (int i = 0; i < 4; ++i)
    Ut[(size_t)(bn * 32 + r + 8 * i) * KTOT + bk * 32 + c] = f2bf(t[c][r + 8 * i]);
}

// Ut k-rows 256..287 = [W(5); zeros] transposed; also WdTg [16][256] bf16.
__global__ __launch_bounds__(1024) void k_prepx(const float* __restrict__ W,
                                                const float* __restrict__ Wd,
                                                unsigned short* __restrict__ Ut,
                                                unsigned short* __restrict__ WdTg) {
  const int idx = blockIdx.x * 1024 + threadIdx.x;
  const int n = idx >> 5;
  const int cc = idx & 31;
  Ut[(size_t)n * KTOT + 256 + cc] = (cc < FEAT) ? f2bf(W[(size_t)cc * NZ + n]) : (unsigned short)0;
  if (blockIdx.x < 4) {
    const int p = idx >> 8;
    const int j = idx & 255;
    WdTg[p * 256 + j] = (p < FEAT) ? f2bf(Wd[(size_t)j * FEAT + p]) : (unsigned short)0;
  }
}

// 256 threads = 4 waves; block = 64 rows x 64 gate-cols (x4 gates).
// 4 blocks/CU co-resident (LDS 37.9KB, VGPR<=128) -> independent barrier
// domains whose stalls interleave (the R10 structure ran 2 phase-locked
// blocks/CU = effectively serial).
__global__ __launch_bounds__(256, 4) void k_lstm(
    const float* __restrict__ x, const float* __restrict__ h0,
    const float* __restrict__ c0, const float* __restrict__ b,
    const float* __restrict__ bd, const unsigned short* __restrict__ Ut,
    const unsigned short* __restrict__ WdTg, float* __restrict__ out) {
  float* out_logits = out;
  float* out_h = out + (size_t)BATCH * FEAT;
  float* out_c = out_h + (size_t)BATCH * NL;

  __shared__ __align__(16) unsigned short A_sh[ROWS * ASTRIDE];  // 37.9 KB (reused)

  const int tid = threadIdx.x;
  const int w = tid >> 6;   // wave 0..3
  const int l = tid & 63;
  const int lrow = l & 15;
  const int lk8 = (l >> 4) * 8;
  const int lq = (l >> 4) * 4;
  const int cg = blockIdx.x & 3;
  const int m0 = (blockIdx.x >> 2) * ROWS;
  const int jcol = cg * COLS + w * 16 + lrow;  // gate col 0..255
  const int wcol = w * 16 + lrow;              // col within block 0..63

  // ---- stage A tile: h0 [64][256] f32 -> bf16, two passes of 8 float4/thread
#pragma unroll
  for (int half = 0; half < 2; ++half) {
    float4 sv[8];
#pragma unroll
    for (int it = 0; it < 8; ++it) {
      const int fi = (half * 8 + it) * 256 + tid;  // 0..4095
      const int row = fi >> 6, c4 = fi & 63;
      sv[it] = *reinterpret_cast<const float4*>(h0 + (size_t)(m0 + row) * NL + c4 * 4);
    }
#pragma unroll
    for (int it = 0; it < 8; ++it) {
      const int fi = (half * 8 + it) * 256 + tid;
      const int row = fi >> 6, c4 = fi & 63;
      *reinterpret_cast<ushort4*>(&A_sh[row * ASTRIDE + c4 * 4]) =
          make_ushort4(f2bf(sv[it].x), f2bf(sv[it].y), f2bf(sv[it].z), f2bf(sv[it].w));
    }
  }
  {
    float xv[8];
#pragma unroll
    for (int it = 0; it < 8; ++it) {
      const int idx = it * 256 + tid;  // 2048 = 64 rows x 32
      const int row = idx >> 5, cc = idx & 31;
      xv[it] = (cc < FEAT) ? x[(size_t)(m0 + row) * FEAT + cc] : 0.f;
    }
#pragma unroll
    for (int it = 0; it < 8; ++it) {
      const int idx = it * 256 + tid;
      const int row = idx >> 5, cc = idx & 31;
      A_sh[row * ASTRIDE + 256 + cc] = f2bf(xv[it]);
    }
  }
  __syncthreads();

  float bb[4];
#pragma unroll
  for (int g = 0; g < 4; ++g) bb[g] = b[g * 256 + jcol];

  // ---- k-loop: JIT B loads, 16 MFMA per kk, setprio around MFMA cluster
  f32x4 acc[4][4];  // [r: row 16-tile][g: gate]
#pragma unroll
  for (int r = 0; r < 4; ++r)
#pragma unroll
    for (int g = 0; g < 4; ++g) acc[r][g] = (f32x4){0.f, 0.f, 0.f, 0.f};

  const unsigned short* bp[4];
#pragma unroll
  for (int g = 0; g < 4; ++g) bp[g] = Ut + (size_t)(g * 256 + jcol) * KTOT + lk8;

#pragma unroll
  for (int kk = 0; kk < 9; ++kk) {
    bf16x8 bf[4];
#pragma unroll
    for (int g = 0; g < 4; ++g)
      bf[g] = *reinterpret_cast<const bf16x8*>(bp[g] + kk * 32);
    __builtin_amdgcn_sched_group_barrier(0x20, 4, 0);  // VMEM_READ x4 first
    bf16x8 af[4];
#pragma unroll
    for (int r = 0; r < 4; ++r)
      af[r] = *reinterpret_cast<const bf16x8*>(
          &A_sh[(r * 16 + lrow) * ASTRIDE + kk * 32 + lk8]);
    __builtin_amdgcn_sched_group_barrier(0x100, 4, 0);  // DS_READ x4
    __builtin_amdgcn_s_setprio(1);
#pragma unroll
    for (int g = 0; g < 4; ++g)
#pragma unroll
      for (int r = 0; r < 4; ++r)
        acc[r][g] = __builtin_amdgcn_mfma_f32_16x16x32_bf16(af[r], bf[g], acc[r][g], 0, 0, 0);
    __builtin_amdgcn_s_setprio(0);
    __builtin_amdgcn_sched_group_barrier(0x8, 16, 0);   // MFMA x16
  }

  // ---- c0 loads (64B-segment clean); other resident blocks cover the latency
  float c0v[4][4];
#pragma unroll
  for (int r = 0; r < 4; ++r)
#pragma unroll
    for (int v = 0; v < 4; ++v)
      c0v[r][v] = c0[(size_t)(m0 + r * 16 + lq + v) * NL + jcol];

  __syncthreads();  // k-loop A_sh reads done -> reuse as f32 t_sh
  float* t_sh = reinterpret_cast<float*>(A_sh);  // [64][68] f32 = 17.4 KB

  // ---- gates: h -> t_sh (scattered LDS), c kept in regs
  float cvs[4][4];
#pragma unroll
  for (int r = 0; r < 4; ++r) {
#pragma unroll
    for (int v = 0; v < 4; ++v) {
      const int mloc = r * 16 + lq + v;
      const float zi = acc[r][0][v] + bb[0];
      const float zf = acc[r][1][v] + bb[1];
      const float zc = acc[r][2][v] + bb[2];
      const float zo = acc[r][3][v] + bb[3];
      const float ig = sigm(zi);
      const float fg = sigm(zf);
      const float og = sigm(zo);
      const float rc = fmaxf(zc, 0.f);
      const float cv = fg * c0v[r][v] + ig * rc;
      const float hv = og * fmaxf(cv, 0.f);
      cvs[r][v] = cv;
      t_sh[mloc * TSTR + wcol] = hv;
    }
  }
  __syncthreads();

  // ---- coalesced h stores: 64 rows x 16 float4 = 1024; 4 per thread
#pragma unroll
  for (int it = 0; it < 4; ++it) {
    const int fi = it * 256 + tid;
    const int row = fi >> 4, c4 = fi & 15;
    const float4 hv4 = *reinterpret_cast<const float4*>(&t_sh[row * TSTR + c4 * 4]);
    *reinterpret_cast<float4*>(out_h + (size_t)(m0 + row) * NL + cg * COLS + c4 * 4) = hv4;
  }

  // ---- partial logits over this block's 64 cols: all 4 waves (16 rows each)
  {
    f32x4 lacc = (f32x4){0.f, 0.f, 0.f, 0.f};
#pragma unroll
    for (int kk2 = 0; kk2 < 2; ++kk2) {
      const float4 hlo = *reinterpret_cast<const float4*>(
          &t_sh[(w * 16 + lrow) * TSTR + kk2 * 32 + lk8]);
      const float4 hhi = *reinterpret_cast<const float4*>(
          &t_sh[(w * 16 + lrow) * TSTR + kk2 * 32 + lk8 + 4]);
      bf16x8 ah;
      ah[0] = (__bf16)hlo.x; ah[1] = (__bf16)hlo.y;
      ah[2] = (__bf16)hlo.z; ah[3] = (__bf16)hlo.w;
      ah[4] = (__bf16)hhi.x; ah[5] = (__bf16)hhi.y;
      ah[6] = (__bf16)hhi.z; ah[7] = (__bf16)hhi.w;
      const bf16x8 bw = *reinterpret_cast<const bf16x8*>(
          &WdTg[lrow * 256 + cg * COLS + kk2 * 32 + lk8]);
      lacc = __builtin_amdgcn_mfma_f32_16x16x32_bf16(ah, bw, lacc, 0, 0, 0);
    }
    if (lrow < FEAT) {
      const float addv = (cg == 0) ? bd[lrow] : 0.f;
#pragma unroll
      for (int v = 0; v < 4; ++v)
        atomicAdd(&out_logits[(size_t)(m0 + w * 16 + lq + v) * FEAT + lrow],
                  lacc[v] + addv);
    }
  }
  __syncthreads();  // h reads done -> overwrite t_sh with c

#pragma unroll
  for (int r = 0; r < 4; ++r)
#pragma unroll
    for (int v = 0; v < 4; ++v)
      t_sh[(r * 16 + lq + v) * TSTR + wcol] = cvs[r][v];
  __syncthreads();

#pragma unroll
  for (int it = 0; it < 4; ++it) {
    const int fi = it * 256 + tid;
    const int row = fi >> 4, c4 = fi & 15;
    const float4 cv4 = *reinterpret_cast<const float4*>(&t_sh[row * TSTR + c4 * 4]);
    *reinterpret_cast<float4*>(out_c + (size_t)(m0 + row) * NL + cg * COLS + c4 * 4) = cv4;
  }
}

extern "C" void kernel_launch(void* const* d_in, const int* in_sizes, int n_in,
                              void* d_out, int out_size, void* d_ws, size_t ws_size,
                              hipStream_t stream) {
  const float* x = (const float*)d_in[0];
  const float* h0 = (const float*)d_in[1];
  const float* c0 = (const float*)d_in[2];
  const float* W = (const float*)d_in[3];
  const float* U = (const float*)d_in[4];
  const float* b = (const float*)d_in[5];
  const float* Wd = (const float*)d_in[6];
  const float* bd = (const float*)d_in[7];
  unsigned short* Ut = (unsigned short*)d_ws;     // 576 KB
  unsigned short* WdTg = Ut + (size_t)NZ * KTOT;  // +8 KB

  k_prep<<<256, 256, 0, stream>>>(U, Ut);
  k_prepx<<<32, 1024, 0, stream>>>(W, Wd, Ut, WdTg);
  hipMemsetAsync(d_out, 0, (size_t)BATCH * FEAT * sizeof(float), stream);
  k_lstm<<<(BATCH / ROWS) * CGRP, 256, 0, stream>>>(x, h0, c0, b, bd, Ut, WdTg,
                                                    (float*)d_out);
}

// Round 13
// 120.769 us; speedup vs baseline: 16.0141x; 1.0910x over previous
//
#include <hip/hip_runtime.h>
#include <hip/hip_bf16.h>

typedef __bf16 bf16x8 __attribute__((ext_vector_type(8)));
typedef float f32x4 __attribute__((ext_vector_type(4)));

#define BATCH 65536
#define NL 256    // N_LSTM
#define NZ 1024   // 4*N_LSTM
#define FEAT 5
#define ROWS 64   // batch rows per block
#define COLS 128  // gate-cols per block
#define CGRP 2    // col-groups per row tile
#define KTOT 288  // 256 (h@U) + 32 (x@W folded: 5 real + 27 zero)
#define ASTRIDE 296  // A_sh row stride (bf16); 592B -> rotated banks
#define CSTR 132     // c0_sh / t_sh row stride (f32); 528B -> rotated banks

__device__ __forceinline__ unsigned short f2bf(float f) {
  __hip_bfloat16 h = __float2bfloat16(f);  // RTNE
  return __builtin_bit_cast(unsigned short, h);
}
__device__ __forceinline__ float sigm(float z) {
  return __builtin_amdgcn_rcpf(1.f + __builtin_amdgcn_exp2f(z * -1.4426950408889634f));
}

// U [256][1024] f32 -> Ut [1024][288] bf16 rows k=0..255 (transposed, k-contiguous)
__global__ __launch_bounds__(256) void k_prep(const float* __restrict__ U,
                                              unsigned short* __restrict__ Ut) {
  __shared__ float t[32][33];
  const int bk = blockIdx.x >> 5;
  const int bn = blockIdx.x & 31;
  const int r = threadIdx.x >> 5;
  const int c = threadIdx.x & 31;
#pragma unroll
  for (int i = 0; i < 4; ++i)
    t[r + 8 * i][c] = U[(size_t)(bk * 32 + r + 8 * i) * NZ + bn * 32 + c];
  __syncthreads();
#pragma unroll
  for (int i = 0; i < 4; ++i)
    Ut[(size_t)(bn * 32 + r + 8 * i) * KTOT + bk * 32 + c] = f2bf(t[c][r + 8 * i]);
}

// Ut k-rows 256..287 = [W(5); zeros] transposed; also WdTg [16][256] bf16.
__global__ __launch_bounds__(1024) void k_prepx(const float* __restrict__ W,
                                                const float* __restrict__ Wd,
                                                unsigned short* __restrict__ Ut,
                                                unsigned short* __restrict__ WdTg) {
  const int idx = blockIdx.x * 1024 + threadIdx.x;
  const int n = idx >> 5;
  const int cc = idx & 31;
  Ut[(size_t)n * KTOT + 256 + cc] = (cc < FEAT) ? f2bf(W[(size_t)cc * NZ + n]) : (unsigned short)0;
  if (blockIdx.x < 4) {
    const int p = idx >> 8;
    const int j = idx & 255;
    WdTg[p * 256 + j] = (p < FEAT) ? f2bf(Wd[(size_t)j * FEAT + p]) : (unsigned short)0;
  }
}

// 512 threads = 8 waves; block = 64 rows x 128 gate-cols (x4 gates).
// XCD-contiguous swizzle: each XCD streams a contiguous 8192-row slab so
// h0 re-reads (cg pair) hit its private L2 and streams stay XCD-local.
// c0 staged to LDS (coalesced) -> no scattered post-kloop VMEM; c output
// written back through the same buffer -> clean full-line stores.
__global__ __launch_bounds__(512, 4) void k_lstm(
    const float* __restrict__ x, const float* __restrict__ h0,
    const float* __restrict__ c0, const float* __restrict__ b,
    const float* __restrict__ bd, const unsigned short* __restrict__ Ut,
    const unsigned short* __restrict__ WdTg, float* __restrict__ out) {
  float* out_logits = out;
  float* out_h = out + (size_t)BATCH * FEAT;
  float* out_c = out_h + (size_t)BATCH * NL;

  __shared__ __align__(16) unsigned short A_sh[ROWS * ASTRIDE];  // 37.9 KB (reused as t_sh)
  __shared__ __align__(16) float c0_sh[ROWS * CSTR];             // 33.8 KB

  const int tid = threadIdx.x;
  const int w = tid >> 6;   // wave 0..7
  const int l = tid & 63;
  const int lrow = l & 15;
  const int lk8 = (l >> 4) * 8;
  const int lq = (l >> 4) * 4;

  // XCD-contiguous remap (bijective: 2048 = 8 XCDs x 256)
  const int nb = ((int)blockIdx.x & 7) * 256 + ((int)blockIdx.x >> 3);
  const int cg = nb & 1;
  const int m0 = (nb >> 1) * ROWS;
  const int jcol = cg * COLS + w * 16 + lrow;  // gate col 0..255
  const int wcol = w * 16 + lrow;              // col within block 0..127

  // ---- stage h0 [64][256] f32 -> bf16 A_sh (8 float4/thread)
  {
    float4 sv[8];
#pragma unroll
    for (int it = 0; it < 8; ++it) {
      const int fi = it * 512 + tid;  // 4096 float4 = 64 rows x 64
      const int row = fi >> 6, c4 = fi & 63;
      sv[it] = *reinterpret_cast<const float4*>(h0 + (size_t)(m0 + row) * NL + c4 * 4);
    }
#pragma unroll
    for (int it = 0; it < 8; ++it) {
      const int fi = it * 512 + tid;
      const int row = fi >> 6, c4 = fi & 63;
      *reinterpret_cast<ushort4*>(&A_sh[row * ASTRIDE + c4 * 4]) =
          make_ushort4(f2bf(sv[it].x), f2bf(sv[it].y), f2bf(sv[it].z), f2bf(sv[it].w));
    }
  }
  // ---- stage c0 cg-slice [64][128] f32 (4 float4/thread, raw copy)
  {
    float4 cv[4];
#pragma unroll
    for (int it = 0; it < 4; ++it) {
      const int fi = it * 512 + tid;  // 2048 float4 = 64 rows x 32
      const int row = fi >> 5, c4 = fi & 31;
      cv[it] = *reinterpret_cast<const float4*>(
          c0 + (size_t)(m0 + row) * NL + cg * COLS + c4 * 4);
    }
#pragma unroll
    for (int it = 0; it < 4; ++it) {
      const int fi = it * 512 + tid;
      const int row = fi >> 5, c4 = fi & 31;
      *reinterpret_cast<float4*>(&c0_sh[row * CSTR + c4 * 4]) = cv[it];
    }
  }
  // ---- stage x -> A_sh cols 256..287
  {
#pragma unroll
    for (int it = 0; it < 4; ++it) {
      const int idx = it * 512 + tid;  // 2048 = 64 rows x 32
      const int row = idx >> 5, cc = idx & 31;
      const float xv = (cc < FEAT) ? x[(size_t)(m0 + row) * FEAT + cc] : 0.f;
      A_sh[row * ASTRIDE + 256 + cc] = f2bf(xv);
    }
  }
  __syncthreads();

  float bb[4];
#pragma unroll
  for (int g = 0; g < 4; ++g) bb[g] = b[g * 256 + jcol];

  // ---- k-loop: JIT B loads, 16 MFMA per kk, setprio around MFMA cluster
  f32x4 acc[4][4];  // [r: row 16-tile][g: gate]
#pragma unroll
  for (int r = 0; r < 4; ++r)
#pragma unroll
    for (int g = 0; g < 4; ++g) acc[r][g] = (f32x4){0.f, 0.f, 0.f, 0.f};

  const unsigned short* bp[4];
#pragma unroll
  for (int g = 0; g < 4; ++g) bp[g] = Ut + (size_t)(g * 256 + jcol) * KTOT + lk8;

#pragma unroll
  for (int kk = 0; kk < 9; ++kk) {
    bf16x8 bf[4];
#pragma unroll
    for (int g = 0; g < 4; ++g)
      bf[g] = *reinterpret_cast<const bf16x8*>(bp[g] + kk * 32);
    __builtin_amdgcn_sched_group_barrier(0x20, 4, 0);  // VMEM_READ x4 first
    bf16x8 af[4];
#pragma unroll
    for (int r = 0; r < 4; ++r)
      af[r] = *reinterpret_cast<const bf16x8*>(
          &A_sh[(r * 16 + lrow) * ASTRIDE + kk * 32 + lk8]);
    __builtin_amdgcn_sched_group_barrier(0x100, 4, 0);  // DS_READ x4
    __builtin_amdgcn_s_setprio(1);
#pragma unroll
    for (int g = 0; g < 4; ++g)
#pragma unroll
      for (int r = 0; r < 4; ++r)
        acc[r][g] = __builtin_amdgcn_mfma_f32_16x16x32_bf16(af[r], bf[g], acc[r][g], 0, 0, 0);
    __builtin_amdgcn_s_setprio(0);
    __builtin_amdgcn_sched_group_barrier(0x8, 16, 0);   // MFMA x16
  }

  __syncthreads();  // k-loop A_sh reads done -> reuse as f32 t_sh (h buffer)
  float* t_sh = reinterpret_cast<float*>(A_sh);  // [64][132] f32 = 33.8 KB

  // ---- gates: c0 from LDS; h -> t_sh, c -> back into c0_sh (same slot)
#pragma unroll
  for (int r = 0; r < 4; ++r) {
#pragma unroll
    for (int v = 0; v < 4; ++v) {
      const int mloc = r * 16 + lq + v;
      const float zi = acc[r][0][v] + bb[0];
      const float zf = acc[r][1][v] + bb[1];
      const float zc = acc[r][2][v] + bb[2];
      const float zo = acc[r][3][v] + bb[3];
      const float ig = sigm(zi);
      const float fg = sigm(zf);
      const float og = sigm(zo);
      const float rc = fmaxf(zc, 0.f);
      const float cv = fg * c0_sh[mloc * CSTR + wcol] + ig * rc;
      const float hv = og * fmaxf(cv, 0.f);
      c0_sh[mloc * CSTR + wcol] = cv;  // self-slot overwrite (same thread)
      t_sh[mloc * CSTR + wcol] = hv;
    }
  }
  __syncthreads();

  // ---- coalesced h & c stores: 4 float4/thread each (full 256B line runs)
#pragma unroll
  for (int it = 0; it < 4; ++it) {
    const int fi = it * 512 + tid;  // 2048 float4 = 64 rows x 32
    const int row = fi >> 5, c4 = fi & 31;
    const float4 hv4 = *reinterpret_cast<const float4*>(&t_sh[row * CSTR + c4 * 4]);
    *reinterpret_cast<float4*>(out_h + (size_t)(m0 + row) * NL + cg * COLS + c4 * 4) = hv4;
    const float4 cv4 = *reinterpret_cast<const float4*>(&c0_sh[row * CSTR + c4 * 4]);
    *reinterpret_cast<float4*>(out_c + (size_t)(m0 + row) * NL + cg * COLS + c4 * 4) = cv4;
  }

  // ---- partial logits over this block's 128 cols: waves 0..3 (16 rows each)
  if (w < 4) {
    f32x4 lacc = (f32x4){0.f, 0.f, 0.f, 0.f};
#pragma unroll
    for (int kk2 = 0; kk2 < 4; ++kk2) {
      const float4 hlo = *reinterpret_cast<const float4*>(
          &t_sh[(w * 16 + lrow) * CSTR + kk2 * 32 + lk8]);
      const float4 hhi = *reinterpret_cast<const float4*>(
          &t_sh[(w * 16 + lrow) * CSTR + kk2 * 32 + lk8 + 4]);
      bf16x8 ah;
      ah[0] = (__bf16)hlo.x; ah[1] = (__bf16)hlo.y;
      ah[2] = (__bf16)hlo.z; ah[3] = (__bf16)hlo.w;
      ah[4] = (__bf16)hhi.x; ah[5] = (__bf16)hhi.y;
      ah[6] = (__bf16)hhi.z; ah[7] = (__bf16)hhi.w;
      const bf16x8 bw = *reinterpret_cast<const bf16x8*>(
          &WdTg[lrow * 256 + cg * COLS + kk2 * 32 + lk8]);
      lacc = __builtin_amdgcn_mfma_f32_16x16x32_bf16(ah, bw, lacc, 0, 0, 0);
    }
    if (lrow < FEAT) {
      const float addv = (cg == 0) ? bd[lrow] : 0.f;
#pragma unroll
      for (int v = 0; v < 4; ++v)
        atomicAdd(&out_logits[(size_t)(m0 + w * 16 + lq + v) * FEAT + lrow],
                  lacc[v] + addv);
    }
  }
}

extern "C" void kernel_launch(void* const* d_in, const int* in_sizes, int n_in,
                              void* d_out, int out_size, void* d_ws, size_t ws_size,
                              hipStream_t stream) {
  const float* x = (const float*)d_in[0];
  const float* h0 = (const float*)d_in[1];
  const float* c0 = (const float*)d_in[2];
  const float* W = (const float*)d_in[3];
  const float* U = (const float*)d_in[4];
  const float* b = (const float*)d_in[5];
  const float* Wd = (const float*)d_in[6];
  const float* bd = (const float*)d_in[7];
  unsigned short* Ut = (unsigned short*)d_ws;     // 576 KB
  unsigned short* WdTg = Ut + (size_t)NZ * KTOT;  // +8 KB

  k_prep<<<256, 256, 0, stream>>>(U, Ut);
  k_prepx<<<32, 1024, 0, stream>>>(W, Wd, Ut, WdTg);
  hipMemsetAsync(d_out, 0, (size_t)BATCH * FEAT * sizeof(float), stream);
  k_lstm<<<(BATCH / ROWS) * CGRP, 512, 0, stream>>>(x, h0, c0, b, bd, Ut, WdTg,
                                                    (float*)d_out);
}